// Round 4
// baseline (221.777 us; speedup 1.0000x reference)
//
#include <hip/hip_runtime.h>
#include <hip/hip_bf16.h>

#define BB 32
#define NN 4096
#define DDIM 64
#define KKR 256

typedef __attribute__((ext_vector_type(8)))  short bf16x8;
typedef __attribute__((ext_vector_type(16))) float f32x16;
typedef __attribute__((ext_vector_type(4)))  float f32x4;

static __device__ inline unsigned short f2bf(float x) {
  union { float f; unsigned u; } v; v.f = x;
  unsigned r = (v.u + 0x7FFFu + ((v.u >> 16) & 1u)) >> 16;   // RNE
  return (unsigned short)r;
}

// pack two fp32 -> one dword of two bf16 (a in low half, b in high half)
static __device__ inline unsigned packbf2(float a, float b) {
  union { float f; unsigned u; } x, y; x.f = a; y.f = b;
  unsigned ua = x.u + 0x7FFFu + ((x.u >> 16) & 1u);
  unsigned ub = y.u + 0x7FFFu + ((y.u >> 16) & 1u);
  return (ua >> 16) | (ub & 0xFFFF0000u);
}

// ---------------------------------------------------------------------------
// pass0: K,V -> KT,VT [b][d][n] bf16 ; E,F -> ET,FT [k][n] bf16.
// Coalesced strided dword reads; 16B packed stores along n.
// blocks: [0,2048) K, [2048,4096) V, [4096,4352) E, [4352,4608) F.
// ---------------------------------------------------------------------------
__global__ __launch_bounds__(256) void pass0_kernel(
    const float* __restrict__ K, const float* __restrict__ V,
    const float* __restrict__ E, const float* __restrict__ F,
    unsigned short* __restrict__ KT, unsigned short* __restrict__ VT,
    unsigned short* __restrict__ ET, unsigned short* __restrict__ FT)
{
  const int id = blockIdx.x;
  const int t  = threadIdx.x;
  const float* src; unsigned short* dst; int stride, n0, col0;
  if (id < 2048) {
    int b = id >> 6, nt = id & 63;
    src = K + (long)b * NN * DDIM; dst = KT + (long)b * DDIM * NN;
    stride = 64; n0 = nt * 64; col0 = 0;
  } else if (id < 4096) {
    int i2 = id - 2048; int b = i2 >> 6, nt = i2 & 63;
    src = V + (long)b * NN * DDIM; dst = VT + (long)b * DDIM * NN;
    stride = 64; n0 = nt * 64; col0 = 0;
  } else if (id < 4352) {
    int i2 = id - 4096; int nt = i2 >> 2, ct = i2 & 3;
    src = E; dst = ET; stride = 256; n0 = nt * 64; col0 = ct * 64;
  } else {
    int i2 = id - 4352; int nt = i2 >> 2, ct = i2 & 3;
    src = F; dst = FT; stride = 256; n0 = nt * 64; col0 = ct * 64;
  }
  const int c = t & 63;            // column (d or k) — lanes consecutive
  const int q = t >> 6;            // n-quad: 16 n-values per thread
  const float* sp = src + (long)(n0 + q * 16) * stride + col0 + c;
  float v[16];
#pragma unroll
  for (int j = 0; j < 16; ++j) v[j] = sp[(long)j * stride];
  unsigned short o[16];
#pragma unroll
  for (int j = 0; j < 16; ++j) o[j] = f2bf(v[j]);
  unsigned short* dp = dst + (long)(col0 + c) * NN + n0 + q * 16;
  *(bf16x8*)dp       = *(const bf16x8*)&o[0];
  *(bf16x8*)(dp + 8) = *(const bf16x8*)&o[8];
}

// ---------------------------------------------------------------------------
// stage1: Kp[b][k][d] = ET[k][:]·KT[b][d][:]   (mat=0, M=256,N=64)
//         Vp[b][d][k] = VT[b][d][:]·FT[k][:]   (mat=1, M=64,N=256)
// 256 blocks = 32 b x 2 mat x 4 n-chunks of 1024; regular stores of fp32
// partials; reduce_cvt sums them.
// ---------------------------------------------------------------------------
__global__ __launch_bounds__(256, 2) void proj_gemm(
    const unsigned short* __restrict__ KT, const unsigned short* __restrict__ VT,
    const unsigned short* __restrict__ ET, const unsigned short* __restrict__ FT,
    float* __restrict__ KpP, float* __restrict__ VpP)
{
  extern __shared__ unsigned short sm[];    // 320 rows x 72 bf16 = 45 KB
  const int blk = blockIdx.x;
  const int chunk = blk & 3, mat = (blk >> 2) & 1, b = blk >> 3;
  const int t = threadIdx.x, w = t >> 6, l = t & 63, h = l >> 5, lr = l & 31;

  const unsigned short *Ag, *Bg; int M; float* Cg;
  if (mat == 0) {
    Ag = ET; Bg = KT + (long)b * DDIM * NN; M = 256;
    Cg = KpP + (long)chunk * (BB * 16384) + b * 16384;
  } else {
    Ag = VT + (long)b * DDIM * NN; Bg = FT; M = 64;
    Cg = VpP + (long)chunk * (BB * 16384) + b * 16384;
  }
  const int mt0 = (mat == 0) ? 2 * w : 0;
  const int nt0 = (mat == 0) ? 0 : 2 * w;

  f32x16 acc[2][2];
#pragma unroll
  for (int i = 0; i < 2; ++i)
#pragma unroll
    for (int j = 0; j < 2; ++j)
#pragma unroll
      for (int q = 0; q < 16; ++q) acc[i][j][q] = 0.f;

  const int n0 = chunk * 1024;
  for (int stg = 0; stg < 16; ++stg) {
    const int nb = n0 + stg * 64;
    __syncthreads();                       // WAR on LDS from previous stage
#pragma unroll
    for (int i = 0; i < 10; ++i) {
      int cidx = i * 256 + t;              // 2560 16B-chunks: 320 rows x 8
      int row = cidx >> 3, off = cidx & 7;
      const unsigned short* g =
          (row < M ? Ag + (long)row * NN : Bg + (long)(row - M) * NN) + nb + off * 8;
      *(bf16x8*)&sm[row * 72 + off * 8] = *(const bf16x8*)g;
    }
    __syncthreads();
#pragma unroll
    for (int kk = 0; kk < 4; ++kk) {
      bf16x8 a0 = *(const bf16x8*)&sm[(mt0 * 32 + lr) * 72 + kk * 16 + h * 8];
      bf16x8 a1 = *(const bf16x8*)&sm[((mt0 + 1) * 32 + lr) * 72 + kk * 16 + h * 8];
      bf16x8 b0 = *(const bf16x8*)&sm[(M + nt0 * 32 + lr) * 72 + kk * 16 + h * 8];
      bf16x8 b1 = *(const bf16x8*)&sm[(M + (nt0 + 1) * 32 + lr) * 72 + kk * 16 + h * 8];
      acc[0][0] = __builtin_amdgcn_mfma_f32_32x32x16_bf16(a0, b0, acc[0][0], 0, 0, 0);
      acc[0][1] = __builtin_amdgcn_mfma_f32_32x32x16_bf16(a0, b1, acc[0][1], 0, 0, 0);
      acc[1][0] = __builtin_amdgcn_mfma_f32_32x32x16_bf16(a1, b0, acc[1][0], 0, 0, 0);
      acc[1][1] = __builtin_amdgcn_mfma_f32_32x32x16_bf16(a1, b1, acc[1][1], 0, 0, 0);
    }
  }
#pragma unroll
  for (int mt = 0; mt < 2; ++mt)
#pragma unroll
    for (int nt = 0; nt < 2; ++nt)
#pragma unroll
      for (int i = 0; i < 16; ++i) {
        int row = (mt0 + mt) * 32 + (i & 3) + 8 * (i >> 2) + 4 * h;  // C/D row
        int col = (nt0 + nt) * 32 + lr;                               // C/D col
        int idx = (mat == 0) ? row * 64 + col : row * 256 + col;
        Cg[idx] = acc[mt][nt][i];
      }
}

// ---------------------------------------------------------------------------
// reduce_cvt: sum 4 fp32 partials -> bf16. blocks [0,256): Kp, [256,512): Vp.
// ---------------------------------------------------------------------------
__global__ __launch_bounds__(256) void reduce_cvt(
    const float* __restrict__ KpP, const float* __restrict__ VpP,
    unsigned short* __restrict__ Kpb, unsigned short* __restrict__ Vpb)
{
  const int blk = blockIdx.x;
  const float* src = (blk < 256) ? KpP : VpP;
  unsigned short* dst = (blk < 256) ? Kpb : Vpb;
  const long i = (long)(blk & 255) * 2048 + threadIdx.x * 8;
  float a[8];
#pragma unroll
  for (int j = 0; j < 8; ++j) a[j] = 0.f;
#pragma unroll
  for (int cch = 0; cch < 4; ++cch) {
    const float4 p0 = *(const float4*)(src + (long)cch * (BB * 16384) + i);
    const float4 p1 = *(const float4*)(src + (long)cch * (BB * 16384) + i + 4);
    a[0] += p0.x; a[1] += p0.y; a[2] += p0.z; a[3] += p0.w;
    a[4] += p1.x; a[5] += p1.y; a[6] += p1.z; a[7] += p1.w;
  }
  unsigned short o[8];
#pragma unroll
  for (int j = 0; j < 8; ++j) o[j] = f2bf(a[j]);
  *(bf16x8*)(dst + i) = *(const bf16x8*)&o[0];
}

// ---------------------------------------------------------------------------
// stage2 (S^T formulation): per block (b, 128-row group), wave w owns rows
// w*32..+32 and the FULL k=256.
//   S^T tile kt: mfma(A=Kpb[k][d], B=Q[r][d]) -> C[m=k][n=r]
//   exp -> register row-sum (16 regs + shfl_xor 32) -> pack bf16 ->
//   half-wave exchange (shfl_xor 32) builds PV B-frags in-register ->
//   PV: mfma(A=Vpb[d][k], B=P^T) -> O^T -> normalize (rowsum at lane) ->
//   32KB XOR-swizzled LDS transpose -> coalesced store.
// No LDS in main path; single barrier before epilogue copy.
// ---------------------------------------------------------------------------
__global__ __launch_bounds__(256, 2) void attn2_kernel(
    const float* __restrict__ Qg, const unsigned short* __restrict__ Kpb,
    const unsigned short* __restrict__ Vpb, float* __restrict__ Og)
{
  __shared__ float O_lds[128 * 64];        // 32 KB

  const int blk = blockIdx.x;
  const int b = blk >> 5, rg = blk & 31;
  const int t = threadIdx.x, w = t >> 6, l = t & 63;
  const int h = l >> 5, lr = l & 31;
  const int rbase = rg * 128 + w * 32;

  // ---- Q B-frags: B[k=d][n=r], lane n=lr -> row rbase+lr, contiguous d
  const float* Qrow = Qg + ((long)b * NN + rbase + lr) * 64;
  bf16x8 Bq[4];
#pragma unroll
  for (int kk = 0; kk < 4; ++kk) {
    float4 x = *(const float4*)(Qrow + kk * 16 + h * 8);
    float4 y = *(const float4*)(Qrow + kk * 16 + h * 8 + 4);
    unsigned short u[8];
    u[0] = f2bf(x.x); u[1] = f2bf(x.y); u[2] = f2bf(x.z); u[3] = f2bf(x.w);
    u[4] = f2bf(y.x); u[5] = f2bf(y.y); u[6] = f2bf(y.z); u[7] = f2bf(y.w);
    Bq[kk] = *(const bf16x8*)u;
  }

  const unsigned short* Kp = Kpb + (long)b * 16384;   // [k=256][d=64]
  const unsigned short* Vp = Vpb + (long)b * 16384;   // [d=64][k=256]

  union UV { uint4 u; bf16x8 v; };
  bf16x8 Bp[16];                    // PV B-frags, one per K=16 chunk
  float rowpart = 0.f;

#pragma unroll
  for (int kt = 0; kt < 8; ++kt) {
    f32x16 s;
#pragma unroll
    for (int q = 0; q < 16; ++q) s[q] = 0.f;
#pragma unroll
    for (int kk = 0; kk < 4; ++kk) {
      bf16x8 A = *(const bf16x8*)(Kp + (long)(kt * 32 + lr) * 64 + kk * 16 + h * 8);
      s = __builtin_amdgcn_mfma_f32_32x32x16_bf16(A, Bq[kk], s, 0, 0, 0);
    }
    // exp(s/8) = exp2(s*log2(e)/8); no max-subtract (|s/8|<~6, fp32-safe)
    float p[16];
#pragma unroll
    for (int q = 0; q < 16; ++q) {
      p[q] = exp2f(s[q] * 0.1803368801f);
      rowpart += p[q];
    }
    // pack pairs along the register (k) direction
    unsigned wv[8];
#pragma unroll
    for (int m = 0; m < 8; ++m) wv[m] = packbf2(p[2 * m], p[2 * m + 1]);
    // half-wave exchange: C-layout k = (q&3)+8*(q>>2)+4h  ->  B-layout k = h*8+j
    unsigned r02 = __shfl_xor(h ? wv[0] : wv[2], 32);
    unsigned r13 = __shfl_xor(h ? wv[1] : wv[3], 32);
    unsigned r46 = __shfl_xor(h ? wv[4] : wv[6], 32);
    unsigned r57 = __shfl_xor(h ? wv[5] : wv[7], 32);
    UV c0, c1;
    if (h == 0) {
      c0.u = uint4{wv[0], wv[1], r02, r13};
      c1.u = uint4{wv[4], wv[5], r46, r57};
    } else {
      c0.u = uint4{r02, r13, wv[2], wv[3]};
      c1.u = uint4{r46, r57, wv[6], wv[7]};
    }
    Bp[kt * 2 + 0] = c0.v;
    Bp[kt * 2 + 1] = c1.v;
  }
  float rowsum = rowpart + __shfl_xor(rowpart, 32);   // full k=256 sum, row=lr

  // ---- PV: O^T[d][r] = sum_k Vp^T[d][k] P^T[k][r]
  f32x16 o[2];
#pragma unroll
  for (int mt = 0; mt < 2; ++mt)
#pragma unroll
    for (int q = 0; q < 16; ++q) o[mt][q] = 0.f;
#pragma unroll
  for (int kc = 0; kc < 16; ++kc) {
    bf16x8 A0 = *(const bf16x8*)(Vp + (long)lr * 256 + kc * 16 + h * 8);
    bf16x8 A1 = *(const bf16x8*)(Vp + (long)(32 + lr) * 256 + kc * 16 + h * 8);
    o[0] = __builtin_amdgcn_mfma_f32_32x32x16_bf16(A0, Bp[kc], o[0], 0, 0, 0);
    o[1] = __builtin_amdgcn_mfma_f32_32x32x16_bf16(A1, Bp[kc], o[1], 0, 0, 0);
  }

  // ---- normalize (rowsum is per-lane) and transpose via swizzled LDS
  const float inv = __builtin_amdgcn_rcpf(rowsum);
  const int r = w * 32 + lr;
#pragma unroll
  for (int mt = 0; mt < 2; ++mt)
#pragma unroll
    for (int qg = 0; qg < 4; ++qg) {
      f32x4 vq;
      vq[0] = o[mt][qg * 4 + 0] * inv;
      vq[1] = o[mt][qg * 4 + 1] * inv;
      vq[2] = o[mt][qg * 4 + 2] * inv;
      vq[3] = o[mt][qg * 4 + 3] * inv;
      int cd = 8 * mt + 2 * qg + h;        // d-chunk (4 dwords each)
      int cp = cd ^ (r & 15);              // XOR swizzle
      *(f32x4*)&O_lds[r * 64 + cp * 4] = vq;
    }
  __syncthreads();

  const long obase = ((long)b * NN + rg * 128) * 64;
#pragma unroll
  for (int i = 0; i < 8; ++i) {
    int ci = i * 256 + t;
    int rr = ci >> 4, cc = ci & 15, cp = cc ^ (rr & 15);
    *(float4*)(Og + obase + rr * 64 + cc * 4) = *(const float4*)&O_lds[rr * 64 + cp * 4];
  }
}

extern "C" void kernel_launch(void* const* d_in, const int* in_sizes, int n_in,
                              void* d_out, int out_size, void* d_ws, size_t ws_size,
                              hipStream_t stream) {
  const float* Q = (const float*)d_in[0];
  const float* K = (const float*)d_in[1];
  const float* V = (const float*)d_in[2];
  const float* E = (const float*)d_in[3];
  const float* F = (const float*)d_in[4];
  float* out = (float*)d_out;

  // workspace layout (54 MB total)
  char* ws = (char*)d_ws;
  float*          KpP = (float*)(ws);                          // 8 MB (4 partials)
  float*          VpP = (float*)(ws + (8l << 20));             // 8 MB
  unsigned short* Kpb = (unsigned short*)(ws + (16l << 20));   // 1 MB
  unsigned short* Vpb = (unsigned short*)(ws + (17l << 20));   // 1 MB
  unsigned short* KT  = (unsigned short*)(ws + (18l << 20));   // 16 MB
  unsigned short* VT  = (unsigned short*)(ws + (34l << 20));   // 16 MB
  unsigned short* ET  = (unsigned short*)(ws + (50l << 20));   // 2 MB
  unsigned short* FT  = (unsigned short*)(ws + (52l << 20));   // 2 MB

  pass0_kernel<<<dim3(4608), dim3(256), 0, stream>>>(K, V, E, F, KT, VT, ET, FT);

  hipFuncSetAttribute((const void*)proj_gemm,
                      hipFuncAttributeMaxDynamicSharedMemorySize, 46080);
  proj_gemm<<<dim3(256), dim3(256), 46080, stream>>>(KT, VT, ET, FT, KpP, VpP);

  reduce_cvt<<<dim3(512), dim3(256), 0, stream>>>(KpP, VpP, Kpb, Vpb);

  attn2_kernel<<<dim3(1024), dim3(256), 0, stream>>>(Q, Kpb, Vpb, out);
}

// Round 5
// 202.051 us; speedup vs baseline: 1.0976x; 1.0976x over previous
//
#include <hip/hip_runtime.h>
#include <hip/hip_bf16.h>

#define BB 32
#define NN 4096
#define DDIM 64

typedef __attribute__((ext_vector_type(8)))  short bf16x8;
typedef __attribute__((ext_vector_type(16))) float f32x16;
typedef __attribute__((ext_vector_type(4)))  float f32x4;

static __device__ inline unsigned short f2bf(float x) {
  union { float f; unsigned u; } v; v.f = x;
  unsigned r = (v.u + 0x7FFFu + ((v.u >> 16) & 1u)) >> 16;   // RNE
  return (unsigned short)r;
}

// packed fp32x2 -> bf16x2 (RNE, v_cvt_pk_bf16_f32 on gfx950)
static __device__ inline unsigned pk(float a, float b) {
  union { __hip_bfloat162 h; unsigned u; } c;
  c.h = __float22bfloat162_rn(float2{a, b});
  return c.u;
}

static __device__ inline bf16x8 pack8(const float* f) {
  union { unsigned u[4]; bf16x8 v; } r;
  r.u[0] = pk(f[0], f[1]); r.u[1] = pk(f[2], f[3]);
  r.u[2] = pk(f[4], f[5]); r.u[3] = pk(f[6], f[7]);
  return r.v;
}

// ---------------------------------------------------------------------------
// proj_gemm (pass0 fused away): MFMA operands loaded DIRECTLY from fp32
// global with the fragment's strided-dword pattern (lanes contiguous in the
// m/n dim -> 128B/half-wave transactions), packed to bf16 in-register.
//   mat=0: Kp[k][d] = sum_n E[n][k] K[b][n][d]   (A=E, B=K)
//   mat=1: Vp[d][k] = sum_n V[b][n][d] F[n][k]   (A=V, B=F)
// 256 blocks = 32b x 2mat x 4 n-chunks of 1024; fp32 partial stores.
// ---------------------------------------------------------------------------
template <int SA, int SB, int OS>
static __device__ inline void proj_body(
    const float* __restrict__ As, const float* __restrict__ Bs,
    float* __restrict__ Cg, int mAdd, int nAdd, int chunk, int h, int lr)
{
  f32x16 acc[2][2];
#pragma unroll
  for (int i = 0; i < 2; ++i)
#pragma unroll
    for (int j = 0; j < 2; ++j)
#pragma unroll
      for (int q = 0; q < 16; ++q) acc[i][j][q] = 0.f;

  const int n0 = chunk * 1024 + h * 8;
  const float* pA = As + (long)n0 * SA + mAdd + lr;
  const float* pB = Bs + (long)n0 * SB + nAdd + lr;

#pragma unroll 2
  for (int tt = 0; tt < 64; ++tt) {              // 64 x K=16
    const float* qA = pA + (long)tt * 16 * SA;
    const float* qB = pB + (long)tt * 16 * SB;
    float a0[8], a1[8], b0[8], b1[8];
#pragma unroll
    for (int j = 0; j < 8; ++j) {
      a0[j] = qA[j * SA];      a1[j] = qA[j * SA + 32];
      b0[j] = qB[j * SB];      b1[j] = qB[j * SB + 32];
    }
    bf16x8 A0 = pack8(a0), A1 = pack8(a1);
    bf16x8 B0 = pack8(b0), B1 = pack8(b1);
    acc[0][0] = __builtin_amdgcn_mfma_f32_32x32x16_bf16(A0, B0, acc[0][0], 0, 0, 0);
    acc[0][1] = __builtin_amdgcn_mfma_f32_32x32x16_bf16(A0, B1, acc[0][1], 0, 0, 0);
    acc[1][0] = __builtin_amdgcn_mfma_f32_32x32x16_bf16(A1, B0, acc[1][0], 0, 0, 0);
    acc[1][1] = __builtin_amdgcn_mfma_f32_32x32x16_bf16(A1, B1, acc[1][1], 0, 0, 0);
  }

#pragma unroll
  for (int mt = 0; mt < 2; ++mt)
#pragma unroll
    for (int nt = 0; nt < 2; ++nt)
#pragma unroll
      for (int i = 0; i < 16; ++i) {
        int ro  = (i & 3) + 8 * (i >> 2) + 4 * h;       // C/D row map
        int row = mAdd + mt * 32 + ro;
        int col = nAdd + nt * 32 + lr;
        Cg[row * OS + col] = acc[mt][nt][i];
      }
}

__global__ __launch_bounds__(256) void proj_gemm(
    const float* __restrict__ Kg, const float* __restrict__ Vg,
    const float* __restrict__ Eg, const float* __restrict__ Fg,
    float* __restrict__ KpP, float* __restrict__ VpP)
{
  const int blk = blockIdx.x;
  const int chunk = blk & 3, mat = (blk >> 2) & 1, b = blk >> 3;
  const int t = threadIdx.x, w = t >> 6, l = t & 63, h = l >> 5, lr = l & 31;

  if (mat == 0) {
    // A=E [n][256] (m=k, wave-split), B=K[b] [n][64] (n-dim=d), C: [k][64]
    proj_body<256, 64, 64>(Eg, Kg + (long)b * NN * DDIM,
                           KpP + (long)chunk * (BB * 16384) + b * 16384,
                           w * 64, 0, chunk, h, lr);
  } else {
    // A=V[b] [n][64] (m=d), B=F [n][256] (n-dim=k, wave-split), C: [d][256]
    proj_body<64, 256, 256>(Vg + (long)b * NN * DDIM, Fg,
                            VpP + (long)chunk * (BB * 16384) + b * 16384,
                            0, w * 64, chunk, h, lr);
  }
}

// ---------------------------------------------------------------------------
// reduce_cvt: sum 4 fp32 partials -> bf16. blocks [0,256): Kp, [256,512): Vp.
// ---------------------------------------------------------------------------
__global__ __launch_bounds__(256) void reduce_cvt(
    const float* __restrict__ KpP, const float* __restrict__ VpP,
    unsigned short* __restrict__ Kpb, unsigned short* __restrict__ Vpb)
{
  const int blk = blockIdx.x;
  const float* src = (blk < 256) ? KpP : VpP;
  unsigned short* dst = (blk < 256) ? Kpb : Vpb;
  const long i = (long)(blk & 255) * 2048 + threadIdx.x * 8;
  float a[8];
#pragma unroll
  for (int j = 0; j < 8; ++j) a[j] = 0.f;
#pragma unroll
  for (int cch = 0; cch < 4; ++cch) {
    const float4 p0 = *(const float4*)(src + (long)cch * (BB * 16384) + i);
    const float4 p1 = *(const float4*)(src + (long)cch * (BB * 16384) + i + 4);
    a[0] += p0.x; a[1] += p0.y; a[2] += p0.z; a[3] += p0.w;
    a[4] += p1.x; a[5] += p1.y; a[6] += p1.z; a[7] += p1.w;
  }
  unsigned short o[8];
#pragma unroll
  for (int j = 0; j < 8; ++j) o[j] = f2bf(a[j]);
  *(bf16x8*)(dst + i) = *(const bf16x8*)&o[0];
}

// ---------------------------------------------------------------------------
// stage2 (S^T, incremental PV): per block (b, 256-row group); wave w owns
// 64 rows (2 row-tiles) and full k=256.
// Per kt (32 k's): load Kp frags once (shared by both row-tiles), QK^T MFMA,
// exp2, pack, half-wave exchange -> PV B-frags consumed IMMEDIATELY into o
// (no live Bp array). Normalize by register rowsum; 64KB swizzled LDS
// transpose; coalesced store.
// ---------------------------------------------------------------------------
__global__ __launch_bounds__(256, 2) void attn2_kernel(
    const float* __restrict__ Qg, const unsigned short* __restrict__ Kpb,
    const unsigned short* __restrict__ Vpb, float* __restrict__ Og)
{
  extern __shared__ float O_lds[];          // 256 x 64 fp32 = 64 KB

  const int blk = blockIdx.x;
  const int b = blk >> 4, rg = blk & 15;
  const int t = threadIdx.x, w = t >> 6, l = t & 63;
  const int h = l >> 5, lr = l & 31;
  const int rbase = rg * 256 + w * 64;

  const unsigned short* Kp = Kpb + (long)b * 16384;   // [k=256][d=64]
  const unsigned short* Vp = Vpb + (long)b * 16384;   // [d=64][k=256]

  // ---- Q B-frags for 2 row-tiles: B[n=r(lane lr)][k=d contiguous]
  bf16x8 Bq[2][4];
#pragma unroll
  for (int rt = 0; rt < 2; ++rt)
#pragma unroll
    for (int kk = 0; kk < 4; ++kk) {
      const float* qp = Qg + ((long)b * NN + rbase + rt * 32 + lr) * 64 + kk * 16 + h * 8;
      float4 x = *(const float4*)qp;
      float4 y = *(const float4*)(qp + 4);
      union { unsigned u[4]; bf16x8 v; } r;
      r.u[0] = pk(x.x, x.y); r.u[1] = pk(x.z, x.w);
      r.u[2] = pk(y.x, y.y); r.u[3] = pk(y.z, y.w);
      Bq[rt][kk] = r.v;
    }

  f32x16 o[2][2];                           // [row-tile][d-tile]
#pragma unroll
  for (int rt = 0; rt < 2; ++rt)
#pragma unroll
    for (int dt = 0; dt < 2; ++dt)
#pragma unroll
      for (int q = 0; q < 16; ++q) o[rt][dt][q] = 0.f;
  float rowpart[2] = {0.f, 0.f};

  union UV { uint4 u; bf16x8 v; };

#pragma unroll
  for (int kt = 0; kt < 8; ++kt) {
    // Kp A-frags (shared by both row-tiles): A[m=k][d contiguous]
    bf16x8 Ak[4];
#pragma unroll
    for (int kk = 0; kk < 4; ++kk)
      Ak[kk] = *(const bf16x8*)(Kp + (long)(kt * 32 + lr) * 64 + kk * 16 + h * 8);
    // Vp A-frags for this k-chunk pair: A[m=d][k contiguous]
    bf16x8 Av[2][2];
#pragma unroll
    for (int dt = 0; dt < 2; ++dt)
#pragma unroll
      for (int kc = 0; kc < 2; ++kc)
        Av[dt][kc] = *(const bf16x8*)(Vp + (long)(dt * 32 + lr) * 256 + (kt * 2 + kc) * 16 + h * 8);

#pragma unroll
    for (int rt = 0; rt < 2; ++rt) {
      f32x16 s;
#pragma unroll
      for (int q = 0; q < 16; ++q) s[q] = 0.f;
#pragma unroll
      for (int kk = 0; kk < 4; ++kk)
        s = __builtin_amdgcn_mfma_f32_32x32x16_bf16(Ak[kk], Bq[rt][kk], s, 0, 0, 0);

      // exp(s/8) = exp2(s*log2(e)/8); no max-subtract (fp32-safe)
      float p[16];
#pragma unroll
      for (int q = 0; q < 16; ++q) p[q] = exp2f(s[q] * 0.1803368801f);
      rowpart[rt] += (((p[0] + p[1]) + (p[2] + p[3])) + ((p[4] + p[5]) + (p[6] + p[7])))
                   + (((p[8] + p[9]) + (p[10] + p[11])) + ((p[12] + p[13]) + (p[14] + p[15])));

      unsigned wv[8];
#pragma unroll
      for (int m = 0; m < 8; ++m) wv[m] = pk(p[2 * m], p[2 * m + 1]);
      // half-wave exchange: C-layout k=(q&3)+8(q>>2)+4h -> B-layout k=h*8+j
      unsigned r02 = __shfl_xor(h ? wv[0] : wv[2], 32);
      unsigned r13 = __shfl_xor(h ? wv[1] : wv[3], 32);
      unsigned r46 = __shfl_xor(h ? wv[4] : wv[6], 32);
      unsigned r57 = __shfl_xor(h ? wv[5] : wv[7], 32);
      UV c0, c1;
      if (h == 0) {
        c0.u = uint4{wv[0], wv[1], r02, r13};
        c1.u = uint4{wv[4], wv[5], r46, r57};
      } else {
        c0.u = uint4{r02, r13, wv[2], wv[3]};
        c1.u = uint4{r46, r57, wv[6], wv[7]};
      }
      // incremental PV: consume immediately, nothing stays live
      o[rt][0] = __builtin_amdgcn_mfma_f32_32x32x16_bf16(Av[0][0], c0.v, o[rt][0], 0, 0, 0);
      o[rt][0] = __builtin_amdgcn_mfma_f32_32x32x16_bf16(Av[0][1], c1.v, o[rt][0], 0, 0, 0);
      o[rt][1] = __builtin_amdgcn_mfma_f32_32x32x16_bf16(Av[1][0], c0.v, o[rt][1], 0, 0, 0);
      o[rt][1] = __builtin_amdgcn_mfma_f32_32x32x16_bf16(Av[1][1], c1.v, o[rt][1], 0, 0, 0);
    }
  }

  // ---- normalize (rowsum at lane=row) and transpose via swizzled LDS
#pragma unroll
  for (int rt = 0; rt < 2; ++rt) {
    float rowsum = rowpart[rt] + __shfl_xor(rowpart[rt], 32);
    float inv = __builtin_amdgcn_rcpf(rowsum);
    const int r = w * 64 + rt * 32 + lr;
#pragma unroll
    for (int dt = 0; dt < 2; ++dt)
#pragma unroll
      for (int qg = 0; qg < 4; ++qg) {
        f32x4 vq;
        vq[0] = o[rt][dt][qg * 4 + 0] * inv;
        vq[1] = o[rt][dt][qg * 4 + 1] * inv;
        vq[2] = o[rt][dt][qg * 4 + 2] * inv;
        vq[3] = o[rt][dt][qg * 4 + 3] * inv;
        int cd = dt * 8 + 2 * qg + h;        // d-chunk (4 dwords)
        int cp = cd ^ (r & 15);              // XOR swizzle
        *(f32x4*)&O_lds[r * 64 + cp * 4] = vq;
      }
  }
  __syncthreads();

  const long obase = ((long)b * NN + rg * 256) * 64;
#pragma unroll
  for (int i = 0; i < 16; ++i) {
    int ci = i * 256 + t;
    int rr = ci >> 4, cc = ci & 15, cp = cc ^ (rr & 15);
    *(float4*)(Og + obase + rr * 64 + cc * 4) = *(const float4*)&O_lds[rr * 64 + cp * 4];
  }
}

extern "C" void kernel_launch(void* const* d_in, const int* in_sizes, int n_in,
                              void* d_out, int out_size, void* d_ws, size_t ws_size,
                              hipStream_t stream) {
  const float* Q = (const float*)d_in[0];
  const float* K = (const float*)d_in[1];
  const float* V = (const float*)d_in[2];
  const float* E = (const float*)d_in[3];
  const float* F = (const float*)d_in[4];
  float* out = (float*)d_out;

  // workspace layout (18 MB total)
  char* ws = (char*)d_ws;
  float*          KpP = (float*)(ws);                          // 8 MB (4 partials)
  float*          VpP = (float*)(ws + (8l << 20));             // 8 MB
  unsigned short* Kpb = (unsigned short*)(ws + (16l << 20));   // 1 MB
  unsigned short* Vpb = (unsigned short*)(ws + (17l << 20));   // 1 MB

  proj_gemm<<<dim3(256), dim3(256), 0, stream>>>(K, V, E, F, KpP, VpP);

  reduce_cvt<<<dim3(512), dim3(256), 0, stream>>>(KpP, VpP, Kpb, Vpb);

  hipFuncSetAttribute((const void*)attn2_kernel,
                      hipFuncAttributeMaxDynamicSharedMemorySize, 65536);
  attn2_kernel<<<dim3(512), dim3(256), 65536, stream>>>(Q, Kpb, Vpb, out);
}